// Round 5
// baseline (289.121 us; speedup 1.0000x reference)
//
#include <hip/hip_runtime.h>
#include <hip/hip_bf16.h>
#include <math.h>

#define B_ 2
#define L_ 4096
#define E_ 1024
#define H_ 16
#define D_ 64
#define CK_ 64
#define NC_ 64

typedef __bf16 bf16x8 __attribute__((ext_vector_type(8)));
typedef __bf16 bf16x4 __attribute__((ext_vector_type(4)));
typedef float  f32x4  __attribute__((ext_vector_type(4)));

__device__ __forceinline__ float fmap1(float x) { return x > 0.f ? x + 1.f : expf(x); }
__device__ __forceinline__ __bf16 f2b(float f) {
    __hip_bfloat16 h = __float2bfloat16(f); return *reinterpret_cast<__bf16*>(&h);
}
__device__ __forceinline__ unsigned short f2u(float f) {
    __hip_bfloat16 h = __float2bfloat16(f); return *reinterpret_cast<unsigned short*>(&h);
}

union U8 { bf16x8 v; __bf16 e[8]; bf16x4 half2[2]; };

__device__ __forceinline__ void async16(const __bf16* g, __bf16* lds) {
    __builtin_amdgcn_global_load_lds(
        (const __attribute__((address_space(1))) void*)g,
        (__attribute__((address_space(3))) void*)lds, 16, 0, 0);
}

// ---------------------------------------------------------------------------
__global__ __launch_bounds__(256) void cast_f32_bf16(const float* __restrict__ in,
                                                     __hip_bfloat16* __restrict__ out, int n) {
    int i = (blockIdx.x * 256 + threadIdx.x) << 2;
    if (i < n) {
        float4 v = *(const float4*)(in + i);
        ushort4 o = {f2u(v.x), f2u(v.y), f2u(v.z), f2u(v.w)};
        *(ushort4*)(out + i) = o;
    }
}

// ---------------------------------------------------------------------------
// MFMA bf16 GEMM: C = A*Bw^T. 128x128 tile, BK=32, 4 waves 2x2, 4x4 16x16x32.
// This round: B (weights, L2-resident) is loaded DIRECTLY global->VGPR with a
// distance-1 register double-buffer (bA/bB, static names per rule #20); only
// A is staged in LDS (3 buffers, 24 KiB total -> occupancy limit moves to
// VGPR ~4 blocks/CU). Manual counted-vmcnt ledger guards A only:
//   per step t issue order: LDB(t+1):4, STGA(t+2):2.
//   end-of-step outstanding = [A(t+1):2, B(t+1):4, A(t+2):2] -> vmcnt(6)
//   forces A(t+1); B(t+1) is waited by the compiler at its register use.
// EPI=1: qkv epilogue (w0: q~=fmap*0.125 -> C, w1: k~=fmap -> C+KT,
// w2: v -> VT only; natural-v C store skipped: no consumer). EPI=0: f32 C.
// ---------------------------------------------------------------------------
#define WVMC(n) do { asm volatile("s_waitcnt vmcnt(" #n ")" ::: "memory"); \
    __builtin_amdgcn_sched_barrier(0); } while (0)

template<int EPI>
__global__ __launch_bounds__(256, 4) void gemm_bd(const __bf16* __restrict__ A,
                                                  const __bf16* __restrict__ Bw,
                                                  void* __restrict__ Cv,
                                                  __hip_bfloat16* __restrict__ KT,
                                                  __hip_bfloat16* __restrict__ VT,
                                                  int M, int N, int K) {
    __shared__ alignas(16) __bf16 As[3][128 * 32];
    const int tid = threadIdx.x;
    const int wave = tid >> 6, lane = tid & 63;
    const int wm = wave >> 1, wn = wave & 1;
    const int lq = lane >> 4, lr = lane & 15;
    const int m0 = blockIdx.y * 128, n0 = blockIdx.x * 128;
    const int NS = K >> 5;            // K-steps of 32 (K=1024 -> 32, even)

    f32x4 acc[4][4];
#pragma unroll
    for (int i = 0; i < 4; ++i)
#pragma unroll
        for (int j = 0; j < 4; ++j) acc[i][j] = (f32x4){0.f, 0.f, 0.f, 0.f};

    const int stg_r = lane >> 2, stg_c = (lane & 3) << 3;
    const __bf16* Ag0 = A + (size_t)(m0 + (wave << 4) + stg_r) * K + stg_c;
    const __bf16* Ag1 = A + (size_t)(m0 + 64 + (wave << 4) + stg_r) * K + stg_c;
    const int dl0 = (wave << 9), dl1 = ((wave + 4) << 9);

    // B direct-from-global base: row n0 + wn*64 + tt*16 + lr, col lq*8 (+k)
    const __bf16* Bp = Bw + (size_t)(n0 + (wn << 6) + lr) * K + (lq << 3);

#define STGA(bi, t) do { const int ko_ = (t) << 5; \
    async16(Ag0 + ko_, &As[bi][dl0]); \
    async16(Ag1 + ko_, &As[bi][dl1]); } while (0)
#define LDB(dst, t) { const int ko_ = (t) << 5; \
    _Pragma("unroll") for (int tt = 0; tt < 4; ++tt) \
        dst[tt] = *(const bf16x8*)&Bp[(size_t)(tt << 4) * K + ko_]; }
#define LDA_MM(breg) { \
    bf16x8 af[4]; \
    _Pragma("unroll") for (int tt = 0; tt < 4; ++tt) \
        af[tt] = *(const bf16x8*)&As[bi][((wm << 6) + (tt << 4) + lr) * 32 + (lq << 3)]; \
    _Pragma("unroll") for (int mt = 0; mt < 4; ++mt) \
    _Pragma("unroll") for (int nt = 0; nt < 4; ++nt) \
        acc[mt][nt] = __builtin_amdgcn_mfma_f32_16x16x32_bf16( \
            af[mt], breg[nt], acc[mt][nt], 0, 0, 0); }
#define ENDSTEP(t) do { \
    if ((t) < NS - 2)       { WVMC(6); } \
    else if ((t) == NS - 2) { WVMC(4); } \
    __builtin_amdgcn_s_barrier(); \
    bi = (bi == 2) ? 0 : bi + 1; \
    bn = (bn == 2) ? 0 : bn + 1; } while (0)

    bf16x8 bA[4], bB[4];

    // prologue: B(0)->bA; stage A(0)->buf0, A(1)->buf1; force B(0)+A(0)
    LDB(bA, 0);
    STGA(0, 0);
    STGA(1, 1);
    WVMC(2);
    __builtin_amdgcn_s_barrier();

    int bi = 0, bn = 2;
    for (int t = 0; t < NS; t += 2) {
        // ---- even step t: compute with bA, prefetch B(t+1)->bB ----
        if (t + 1 < NS) LDB(bB, t + 1);
        if (t + 2 < NS) STGA(bn, t + 2);
        LDA_MM(bA);
        ENDSTEP(t);
        // ---- odd step t+1: compute with bB, prefetch B(t+2)->bA ----
        if (t + 2 < NS) LDB(bA, t + 2);
        if (t + 3 < NS) STGA(bn, t + 3);
        LDA_MM(bB);
        ENDSTEP(t + 1);
    }

#pragma unroll
    for (int mt = 0; mt < 4; ++mt) {
#pragma unroll
        for (int nt = 0; nt < 4; ++nt) {
            int m = m0 + (wm << 6) + (mt << 4) + (lq << 2);
            int n = n0 + (wn << 6) + (nt << 4) + lr;
            if (EPI == 1) {
                int w = n >> 10, hh = (n >> 6) & 15, dd = n & 63;
                float vv[4];
#pragma unroll
                for (int r = 0; r < 4; ++r) {
                    float v = acc[mt][nt][r];
                    if (w == 0)      v = fmap1(v) * 0.125f;
                    else if (w == 1) v = fmap1(v);
                    vv[r] = v;
                    if (w <= 1)   // natural v never read downstream -> skip
                        ((__hip_bfloat16*)Cv)[(size_t)(m + r) * N + n] = __float2bfloat16(v);
                }
                if (w >= 1) {   // transposed copies: w1 -> KT, w2 -> VT
                    int b = m >> 12, l = m & 4095;
                    __hip_bfloat16* T = (w == 1) ? KT : VT;
                    ushort4 u = {f2u(vv[0]), f2u(vv[1]), f2u(vv[2]), f2u(vv[3])};
                    *(ushort4*)&T[((size_t)((b * 16 + hh) * 64 + dd) << 12) + l] = u;
                }
            } else {
#pragma unroll
                for (int r = 0; r < 4; ++r)
                    ((float*)Cv)[(size_t)(m + r) * N + n] = acc[mt][nt][r];
            }
        }
    }
#undef STGA
#undef LDB
#undef LDA_MM
#undef ENDSTEP
}

// ---------------------------------------------------------------------------
// MFMA per-chunk state: S_T[e][d] = sum_l VT[e][l]*KT[d][l]; Z[d] = sum_l KT[d][l].
// grid (16, 32); wave = chunk c = bx*4+w. Stores bf16.
// ---------------------------------------------------------------------------
__global__ __launch_bounds__(256) void chunk_state_mfma(const __hip_bfloat16* __restrict__ KTh,
                                                        const __hip_bfloat16* __restrict__ VTh,
                                                        __hip_bfloat16* __restrict__ Sb,
                                                        __hip_bfloat16* __restrict__ Zb) {
    const int tid = threadIdx.x, wave = tid >> 6, lane = tid & 63;
    const int quad = lane >> 4, lr = lane & 15;
    const int bh = blockIdx.y;
    const int c = blockIdx.x * 4 + wave;
    const __bf16* KT = (const __bf16*)KTh;
    const __bf16* VT = (const __bf16*)VTh;

    bf16x8 vt[4][2], kt[4][2];
#pragma unroll
    for (int t = 0; t < 4; ++t)
#pragma unroll
        for (int kk = 0; kk < 2; ++kk) {
            size_t rowoff = ((size_t)(bh * 64 + t * 16 + lr) << 12) + c * CK_ + kk * 32 + quad * 8;
            vt[t][kk] = *(const bf16x8*)&VT[rowoff];
            kt[t][kk] = *(const bf16x8*)&KT[rowoff];
        }

    U8 of;
#pragma unroll
    for (int j = 0; j < 8; ++j) of.e[j] = f2b(1.0f);

    __hip_bfloat16* Sp = Sb + ((size_t)(c * 32 + bh) << 12);
#pragma unroll
    for (int es = 0; es < 4; ++es) {
#pragma unroll
        for (int dt = 0; dt < 4; ++dt) {
            f32x4 acc = (f32x4){0.f, 0.f, 0.f, 0.f};
            acc = __builtin_amdgcn_mfma_f32_16x16x32_bf16(vt[es][0], kt[dt][0], acc, 0, 0, 0);
            acc = __builtin_amdgcn_mfma_f32_16x16x32_bf16(vt[es][1], kt[dt][1], acc, 0, 0, 0);
#pragma unroll
            for (int r = 0; r < 4; ++r)
                Sp[(es * 16 + quad * 4 + r) * 64 + dt * 16 + lr] =
                    __float2bfloat16(acc[r]);
        }
    }
#pragma unroll
    for (int dt = 0; dt < 4; ++dt) {
        f32x4 z = (f32x4){0.f, 0.f, 0.f, 0.f};
        z = __builtin_amdgcn_mfma_f32_16x16x32_bf16(kt[dt][0], of.v, z, 0, 0, 0);
        z = __builtin_amdgcn_mfma_f32_16x16x32_bf16(kt[dt][1], of.v, z, 0, 0, 0);
        if (lr == 0) {
#pragma unroll
            for (int r = 0; r < 4; ++r)
                Zb[((c * 32 + bh) << 6) + dt * 16 + quad * 4 + r] = __float2bfloat16(z[r]);
        }
    }
}

// ---------------------------------------------------------------------------
// Exclusive prefix over 64 chunks, register-resident: 64 independent loads
// (pipelined into ~one HBM latency) -> in-register scan -> 64 stores.
// grid (16, 32).
// ---------------------------------------------------------------------------
__global__ __launch_bounds__(256) void prefix64(__hip_bfloat16* __restrict__ Sb,
                                                __hip_bfloat16* __restrict__ Zb) {
    const int bh = blockIdx.y;
    const int idx = blockIdx.x * 256 + threadIdx.x;   // 0..4095
    float v[NC_];
#pragma unroll
    for (int c = 0; c < NC_; ++c)
        v[c] = __bfloat162float(Sb[((size_t)(c * 32 + bh) << 12) + idx]);
    float run = 0.f;
#pragma unroll
    for (int c = 0; c < NC_; ++c) {
        Sb[((size_t)(c * 32 + bh) << 12) + idx] = __float2bfloat16(run);
        run += v[c];
    }
    if (blockIdx.x == 0 && threadIdx.x < 64) {
        float z[NC_];
#pragma unroll
        for (int c = 0; c < NC_; ++c)
            z[c] = __bfloat162float(Zb[((c * 32 + bh) << 6) + threadIdx.x]);
        float zr = 0.f;
#pragma unroll
        for (int c = 0; c < NC_; ++c) {
            Zb[((c * 32 + bh) << 6) + threadIdx.x] = __float2bfloat16(zr);
            zr += z[c];
        }
    }
}

// ---------------------------------------------------------------------------
// MFMA attention output (R8-verified structure; S/Z bf16 vector loads).
// ---------------------------------------------------------------------------
__global__ __launch_bounds__(256) void attn_out_mfma(const __hip_bfloat16* __restrict__ qvh,
                                                     const __hip_bfloat16* __restrict__ Sbh,
                                                     const __hip_bfloat16* __restrict__ Zbh,
                                                     const __hip_bfloat16* __restrict__ VTh,
                                                     __hip_bfloat16* __restrict__ attn) {
    __shared__ __bf16 Pbuf[4 * 64 * 68];
    const int tid = threadIdx.x, wave = tid >> 6, lane = tid & 63;
    const int quad = lane >> 4, lr = lane & 15;
    const int bh = blockIdx.y, b = bh >> 4, h = bh & 15;
    const int c = blockIdx.x * 4 + wave;
    const size_t t0 = (size_t)b * L_ + c * CK_;
    const __bf16* qb = (const __bf16*)qvh;
    const __bf16* Sb = (const __bf16*)Sbh;
    const __bf16* Zb = (const __bf16*)Zbh;
    const __bf16* VT = (const __bf16*)VTh;
    __bf16* P = Pbuf + wave * (64 * 68);

    bf16x8 qf[4][2];
#pragma unroll
    for (int ls = 0; ls < 4; ++ls)
#pragma unroll
        for (int kk = 0; kk < 2; ++kk)
            qf[ls][kk] = *(const bf16x8*)&qb[(t0 + ls * 16 + lr) * 3072 + h * 64 + kk * 32 + quad * 8];

    f32x4 num[4][4], den[4];
#pragma unroll
    for (int i = 0; i < 4; ++i) {
        den[i] = (f32x4){0.f, 0.f, 0.f, 0.f};
#pragma unroll
        for (int j = 0; j < 4; ++j) num[i][j] = (f32x4){0.f, 0.f, 0.f, 0.f};
    }

    bf16x8 zf[2];
#pragma unroll
    for (int kk = 0; kk < 2; ++kk)
        zf[kk] = *(const bf16x8*)&Zb[((size_t)(c * 32 + bh) << 6) + kk * 32 + quad * 8];
#pragma unroll
    for (int ls = 0; ls < 4; ++ls)
#pragma unroll
        for (int kk = 0; kk < 2; ++kk)
            den[ls] = __builtin_amdgcn_mfma_f32_16x16x32_bf16(qf[ls][kk], zf[kk], den[ls], 0, 0, 0);

#pragma unroll
    for (int es = 0; es < 4; ++es) {
        bf16x8 sf[2];
#pragma unroll
        for (int kk = 0; kk < 2; ++kk)
            sf[kk] = *(const bf16x8*)&Sb[((size_t)(c * 32 + bh) << 12)
                                         + (es * 16 + lr) * 64 + kk * 32 + quad * 8];
#pragma unroll
        for (int ls = 0; ls < 4; ++ls)
#pragma unroll
            for (int kk = 0; kk < 2; ++kk)
                num[ls][es] = __builtin_amdgcn_mfma_f32_16x16x32_bf16(
                    qf[ls][kk], sf[kk], num[ls][es], 0, 0, 0);
    }

    bf16x8 kf[4][2];
#pragma unroll
    for (int ms = 0; ms < 4; ++ms)
#pragma unroll
        for (int kk = 0; kk < 2; ++kk)
            kf[ms][kk] = *(const bf16x8*)&qb[(t0 + ms * 16 + lr) * 3072 + 1024 + h * 64 + kk * 32 + quad * 8];

#pragma unroll
    for (int ls = 0; ls < 4; ++ls) {
#pragma unroll
        for (int ms = 0; ms < 4; ++ms) {
            int off = (ls * 16 + lr) * 68 + ms * 16 + quad * 4;
            if (ms <= ls) {
                f32x4 pt = (f32x4){0.f, 0.f, 0.f, 0.f};
                pt = __builtin_amdgcn_mfma_f32_16x16x32_bf16(kf[ms][0], qf[ls][0], pt, 0, 0, 0);
                pt = __builtin_amdgcn_mfma_f32_16x16x32_bf16(kf[ms][1], qf[ls][1], pt, 0, 0, 0);
                ushort4 u;
                if (ms == ls) {
                    u.x = (quad * 4 + 0 > lr) ? 0 : f2u(pt[0]);
                    u.y = (quad * 4 + 1 > lr) ? 0 : f2u(pt[1]);
                    u.z = (quad * 4 + 2 > lr) ? 0 : f2u(pt[2]);
                    u.w = (quad * 4 + 3 > lr) ? 0 : f2u(pt[3]);
                } else {
                    u = (ushort4){f2u(pt[0]), f2u(pt[1]), f2u(pt[2]), f2u(pt[3])};
                }
                *(ushort4*)&P[off] = u;
            } else {
                *(ushort4*)&P[off] = (ushort4){0, 0, 0, 0};
            }
        }
    }

    U8 of;
#pragma unroll
    for (int j = 0; j < 8; ++j) of.e[j] = f2b(1.0f);

#pragma unroll
    for (int kk = 0; kk < 2; ++kk) {
        U8 pf[4];
#pragma unroll
        for (int ls = 0; ls < 4; ++ls) {
            pf[ls].half2[0] = *(const bf16x4*)&P[(ls * 16 + lr) * 68 + kk * 32 + quad * 8];
            pf[ls].half2[1] = *(const bf16x4*)&P[(ls * 16 + lr) * 68 + kk * 32 + quad * 8 + 4];
        }
        bf16x8 vf[4];
#pragma unroll
        for (int es = 0; es < 4; ++es)
            vf[es] = *(const bf16x8*)&VT[((size_t)((b * 16 + h) * 64 + es * 16 + lr) << 12)
                                         + c * CK_ + kk * 32 + quad * 8];
#pragma unroll
        for (int ls = 0; ls < 4; ++ls) {
            den[ls] = __builtin_amdgcn_mfma_f32_16x16x32_bf16(pf[ls].v, of.v, den[ls], 0, 0, 0);
#pragma unroll
            for (int es = 0; es < 4; ++es)
                num[ls][es] = __builtin_amdgcn_mfma_f32_16x16x32_bf16(
                    pf[ls].v, vf[es], num[ls][es], 0, 0, 0);
        }
    }

#pragma unroll
    for (int ls = 0; ls < 4; ++ls) {
#pragma unroll
        for (int r = 0; r < 4; ++r) {
            float inv = 1.f / fmaxf(den[ls][r], 1e-6f);
            size_t row = (t0 + ls * 16 + quad * 4 + r) * 1024 + h * 64;
#pragma unroll
            for (int es = 0; es < 4; ++es)
                attn[row + es * 16 + lr] = __float2bfloat16(num[ls][es][r] * inv);
        }
    }
}

// ---------------------------------------------------------------------------
extern "C" void kernel_launch(void* const* d_in, const int* in_sizes, int n_in,
                              void* d_out, int out_size, void* d_ws, size_t ws_size,
                              hipStream_t stream) {
    (void)ws_size; (void)out_size;
    const float *x = nullptr, *Wqkv = nullptr, *Wout = nullptr;
    for (int i = 0; i < n_in; ++i) {
        if (in_sizes[i] == 8388608)      x    = (const float*)d_in[i];
        else if (in_sizes[i] == 3145728) Wqkv = (const float*)d_in[i];
        else if (in_sizes[i] == 1048576) Wout = (const float*)d_in[i];
    }

    __hip_bfloat16* ws16  = (__hip_bfloat16*)d_ws;
    __hip_bfloat16* xb    = ws16;                       //  8388608 (attn aliases)
    __hip_bfloat16* attn  = ws16;
    __hip_bfloat16* Wqkvb = ws16 + 8388608;             //  3145728
    __hip_bfloat16* Woutb = Wqkvb + 3145728;            //  1048576
    __hip_bfloat16* qv    = Woutb + 1048576;            // 25165824
    __hip_bfloat16* VT    = qv + 25165824;              //  8388608
    __hip_bfloat16* KT    = VT + 8388608;               //  8388608
    __hip_bfloat16* Sb    = KT + 8388608;               //  8388608
    __hip_bfloat16* Zb    = Sb + 8388608;               //   131072

    cast_f32_bf16<<<8388608 / 1024, 256, 0, stream>>>(x, xb, 8388608);
    cast_f32_bf16<<<3145728 / 1024, 256, 0, stream>>>(Wqkv, Wqkvb, 3145728);
    cast_f32_bf16<<<1048576 / 1024, 256, 0, stream>>>(Wout, Woutb, 1048576);

    // 1. qv (+KT,+VT) = feature_map(xb @ Wqkvb^T)  — B-direct, A 3-buf LDS
    gemm_bd<1><<<dim3(3072 / 128, 8192 / 128), 256, 0, stream>>>(
        (const __bf16*)xb, (const __bf16*)Wqkvb, qv, KT, VT, B_ * L_, 3 * E_, E_);
    // 2. per-chunk states via MFMA (bf16 out)
    chunk_state_mfma<<<dim3(16, B_ * H_), 256, 0, stream>>>(KT, VT, Sb, Zb);
    // 3. exclusive prefix over 64 chunks (register-resident scan)
    prefix64<<<dim3(16, B_ * H_), 256, 0, stream>>>(Sb, Zb);
    // 4. MFMA attention output -> attn bf16
    attn_out_mfma<<<dim3(16, B_ * H_), 256, 0, stream>>>(qv, Sb, Zb, VT, attn);
    // 5. out = attn @ Woutb^T, f32 — same B-direct template
    gemm_bd<0><<<dim3(1024 / 128, 8192 / 128), 256, 0, stream>>>(
        (const __bf16*)attn, (const __bf16*)Woutb, d_out, nullptr, nullptr, B_ * L_, E_, E_);
}

// Round 6
// 232.789 us; speedup vs baseline: 1.2420x; 1.2420x over previous
//
#include <hip/hip_runtime.h>
#include <hip/hip_bf16.h>
#include <math.h>

#define B_ 2
#define L_ 4096
#define E_ 1024
#define H_ 16
#define D_ 64
#define CK_ 64
#define NC_ 64

typedef __bf16 bf16x8 __attribute__((ext_vector_type(8)));
typedef __bf16 bf16x4 __attribute__((ext_vector_type(4)));
typedef float  f32x4  __attribute__((ext_vector_type(4)));

__device__ __forceinline__ float fmap1(float x) { return x > 0.f ? x + 1.f : expf(x); }
__device__ __forceinline__ __bf16 f2b(float f) {
    __hip_bfloat16 h = __float2bfloat16(f); return *reinterpret_cast<__bf16*>(&h);
}
__device__ __forceinline__ unsigned short f2u(float f) {
    __hip_bfloat16 h = __float2bfloat16(f); return *reinterpret_cast<unsigned short*>(&h);
}

union U8 { bf16x8 v; __bf16 e[8]; bf16x4 half2[2]; };

__device__ __forceinline__ void async16(const __bf16* g, __bf16* lds) {
    __builtin_amdgcn_global_load_lds(
        (const __attribute__((address_space(1))) void*)g,
        (__attribute__((address_space(3))) void*)lds, 16, 0, 0);
}

// ---------------------------------------------------------------------------
__global__ __launch_bounds__(256) void cast_f32_bf16(const float* __restrict__ in,
                                                     __hip_bfloat16* __restrict__ out, int n) {
    int i = (blockIdx.x * 256 + threadIdx.x) << 2;
    if (i < n) {
        float4 v = *(const float4*)(in + i);
        ushort4 o = {f2u(v.x), f2u(v.y), f2u(v.z), f2u(v.w)};
        *(ushort4*)(out + i) = o;
    }
}

// ---------------------------------------------------------------------------
// MFMA bf16 GEMM: C = A*Bw^T. 128x128 tile, BK=32, 4 waves 2x2, 4x4 16x16x32.
// r4-verified staging: 3 LDS buffers (48 KiB, 3 blocks/CU), distance-2
// prefetch, counted vmcnt(4) (never 0 in loop), one raw s_barrier/step.
// r6 additions: (1) bijective XCD-chunked blockIdx swizzle (nwg%8==0 for
// both call sites) so each XCD works a contiguous wgid range -> A-panel
// L2 locality; (2) EPI=1 skips the natural-v C store (no consumer).
// ---------------------------------------------------------------------------
#define WVMC(n) do { asm volatile("s_waitcnt vmcnt(" #n ")" ::: "memory"); \
    __builtin_amdgcn_sched_barrier(0); } while (0)

template<int EPI>
__global__ __launch_bounds__(256) void gemm_mfma3(const __bf16* __restrict__ A,
                                                  const __bf16* __restrict__ Bw,
                                                  void* __restrict__ Cv,
                                                  __hip_bfloat16* __restrict__ KT,
                                                  __hip_bfloat16* __restrict__ VT,
                                                  int M, int N, int K) {
    __shared__ alignas(16) __bf16 As[3][128 * 32];
    __shared__ alignas(16) __bf16 Bs[3][128 * 32];
    const int tid = threadIdx.x;
    const int wave = tid >> 6, lane = tid & 63;
    const int wm = wave >> 1, wn = wave & 1;
    const int lq = lane >> 4, lr = lane & 15;

    // XCD-chunked bijective swizzle (T1, m157/m204): nwg % 8 == 0 here.
    const int nwg = gridDim.x * gridDim.y;
    const int bid = blockIdx.y * gridDim.x + blockIdx.x;
    const int cpx = nwg >> 3;
    const int wgid = (bid & 7) * cpx + (bid >> 3);
    const int bx = wgid % gridDim.x, by = wgid / gridDim.x;
    const int m0 = by * 128, n0 = bx * 128;

    const int NS = K >> 5;

    f32x4 acc[4][4];
#pragma unroll
    for (int i = 0; i < 4; ++i)
#pragma unroll
        for (int j = 0; j < 4; ++j) acc[i][j] = (f32x4){0.f, 0.f, 0.f, 0.f};

    const int stg_r = lane >> 2, stg_c = (lane & 3) << 3;
    const __bf16* Ag0 = A + (size_t)(m0 + (wave << 4) + stg_r) * K + stg_c;
    const __bf16* Ag1 = A + (size_t)(m0 + 64 + (wave << 4) + stg_r) * K + stg_c;
    const __bf16* Bg0 = Bw + (size_t)(n0 + (wave << 4) + stg_r) * K + stg_c;
    const __bf16* Bg1 = Bw + (size_t)(n0 + 64 + (wave << 4) + stg_r) * K + stg_c;
    const int dl0 = (wave << 9), dl1 = ((wave + 4) << 9);  // per-wave LDS dest (elems)

#define STG3(bi, t) do { const int ko_ = (t) << 5; \
    async16(Ag0 + ko_, &As[bi][dl0]); \
    async16(Ag1 + ko_, &As[bi][dl1]); \
    async16(Bg0 + ko_, &Bs[bi][dl0]); \
    async16(Bg1 + ko_, &Bs[bi][dl1]); } while (0)

    // prologue: fill buf0, buf1; force buf0 (leave buf1's 4 calls in flight)
    STG3(0, 0);
    STG3(1, 1);
    WVMC(4);
    __builtin_amdgcn_s_barrier();

    int bi = 0, bn = 2;           // bi: compute buffer; bn: dest for stage(t+2)
    for (int t = 0; t < NS; ++t) {
        if (t + 2 < NS) STG3(bn, t + 2);
        bf16x8 af[4], bfr[4];
#pragma unroll
        for (int tt = 0; tt < 4; ++tt) {
            af[tt]  = *(const bf16x8*)&As[bi][((wm << 6) + (tt << 4) + lr) * 32 + (lq << 3)];
            bfr[tt] = *(const bf16x8*)&Bs[bi][((wn << 6) + (tt << 4) + lr) * 32 + (lq << 3)];
        }
#pragma unroll
        for (int mt = 0; mt < 4; ++mt)
#pragma unroll
            for (int nt = 0; nt < 4; ++nt)
                acc[mt][nt] = __builtin_amdgcn_mfma_f32_16x16x32_bf16(
                    af[mt], bfr[nt], acc[mt][nt], 0, 0, 0);
        if (t < NS - 2)       { WVMC(4); }   // force stage(t+1); keep stage(t+2) in flight
        else if (t == NS - 2) { WVMC(0); }   // last prefetch must land
        __builtin_amdgcn_s_barrier();
        bi = (bi == 2) ? 0 : bi + 1;
        bn = (bn == 2) ? 0 : bn + 1;
    }

#pragma unroll
    for (int mt = 0; mt < 4; ++mt) {
#pragma unroll
        for (int nt = 0; nt < 4; ++nt) {
            int m = m0 + (wm << 6) + (mt << 4) + (lq << 2);
            int n = n0 + (wn << 6) + (nt << 4) + lr;
            if (EPI == 1) {
                int w = n >> 10, hh = (n >> 6) & 15, dd = n & 63;
                float vv[4];
#pragma unroll
                for (int r = 0; r < 4; ++r) {
                    float v = acc[mt][nt][r];
                    if (w == 0)      v = fmap1(v) * 0.125f;
                    else if (w == 1) v = fmap1(v);
                    vv[r] = v;
                    if (w <= 1)   // natural v never read downstream -> skip store
                        ((__hip_bfloat16*)Cv)[(size_t)(m + r) * N + n] = __float2bfloat16(v);
                }
                if (w >= 1) {   // transposed copies: w1 -> KT, w2 -> VT
                    int b = m >> 12, l = m & 4095;
                    __hip_bfloat16* T = (w == 1) ? KT : VT;
                    ushort4 u = {f2u(vv[0]), f2u(vv[1]), f2u(vv[2]), f2u(vv[3])};
                    *(ushort4*)&T[((size_t)((b * 16 + hh) * 64 + dd) << 12) + l] = u;
                }
            } else {
#pragma unroll
                for (int r = 0; r < 4; ++r)
                    ((float*)Cv)[(size_t)(m + r) * N + n] = acc[mt][nt][r];
            }
        }
    }
#undef STG3
}

// ---------------------------------------------------------------------------
// MFMA per-chunk state: S_T[e][d] = sum_l VT[e][l]*KT[d][l]; Z[d] = sum_l KT[d][l].
// grid (16, 32); wave = chunk c = bx*4+w. Stores bf16.
// ---------------------------------------------------------------------------
__global__ __launch_bounds__(256) void chunk_state_mfma(const __hip_bfloat16* __restrict__ KTh,
                                                        const __hip_bfloat16* __restrict__ VTh,
                                                        __hip_bfloat16* __restrict__ Sb,
                                                        __hip_bfloat16* __restrict__ Zb) {
    const int tid = threadIdx.x, wave = tid >> 6, lane = tid & 63;
    const int quad = lane >> 4, lr = lane & 15;
    const int bh = blockIdx.y;
    const int c = blockIdx.x * 4 + wave;
    const __bf16* KT = (const __bf16*)KTh;
    const __bf16* VT = (const __bf16*)VTh;

    bf16x8 vt[4][2], kt[4][2];
#pragma unroll
    for (int t = 0; t < 4; ++t)
#pragma unroll
        for (int kk = 0; kk < 2; ++kk) {
            size_t rowoff = ((size_t)(bh * 64 + t * 16 + lr) << 12) + c * CK_ + kk * 32 + quad * 8;
            vt[t][kk] = *(const bf16x8*)&VT[rowoff];
            kt[t][kk] = *(const bf16x8*)&KT[rowoff];
        }

    U8 of;
#pragma unroll
    for (int j = 0; j < 8; ++j) of.e[j] = f2b(1.0f);

    __hip_bfloat16* Sp = Sb + ((size_t)(c * 32 + bh) << 12);
#pragma unroll
    for (int es = 0; es < 4; ++es) {
#pragma unroll
        for (int dt = 0; dt < 4; ++dt) {
            f32x4 acc = (f32x4){0.f, 0.f, 0.f, 0.f};
            acc = __builtin_amdgcn_mfma_f32_16x16x32_bf16(vt[es][0], kt[dt][0], acc, 0, 0, 0);
            acc = __builtin_amdgcn_mfma_f32_16x16x32_bf16(vt[es][1], kt[dt][1], acc, 0, 0, 0);
#pragma unroll
            for (int r = 0; r < 4; ++r)
                Sp[(es * 16 + quad * 4 + r) * 64 + dt * 16 + lr] =
                    __float2bfloat16(acc[r]);
        }
    }
#pragma unroll
    for (int dt = 0; dt < 4; ++dt) {
        f32x4 z = (f32x4){0.f, 0.f, 0.f, 0.f};
        z = __builtin_amdgcn_mfma_f32_16x16x32_bf16(kt[dt][0], of.v, z, 0, 0, 0);
        z = __builtin_amdgcn_mfma_f32_16x16x32_bf16(kt[dt][1], of.v, z, 0, 0, 0);
        if (lr == 0) {
#pragma unroll
            for (int r = 0; r < 4; ++r)
                Zb[((c * 32 + bh) << 6) + dt * 16 + quad * 4 + r] = __float2bfloat16(z[r]);
        }
    }
}

// ---------------------------------------------------------------------------
// Exclusive prefix over 64 chunks, register-resident: 64 independent loads
// (pipelined into ~one latency) -> in-register scan -> 64 stores.
// grid (16, 32).
// ---------------------------------------------------------------------------
__global__ __launch_bounds__(256) void prefix64(__hip_bfloat16* __restrict__ Sb,
                                                __hip_bfloat16* __restrict__ Zb) {
    const int bh = blockIdx.y;
    const int idx = blockIdx.x * 256 + threadIdx.x;   // 0..4095
    float v[NC_];
#pragma unroll
    for (int c = 0; c < NC_; ++c)
        v[c] = __bfloat162float(Sb[((size_t)(c * 32 + bh) << 12) + idx]);
    float run = 0.f;
#pragma unroll
    for (int c = 0; c < NC_; ++c) {
        Sb[((size_t)(c * 32 + bh) << 12) + idx] = __float2bfloat16(run);
        run += v[c];
    }
    if (blockIdx.x == 0 && threadIdx.x < 64) {
        float z[NC_];
#pragma unroll
        for (int c = 0; c < NC_; ++c)
            z[c] = __bfloat162float(Zb[((c * 32 + bh) << 6) + threadIdx.x]);
        float zr = 0.f;
#pragma unroll
        for (int c = 0; c < NC_; ++c) {
            Zb[((c * 32 + bh) << 6) + threadIdx.x] = __float2bfloat16(zr);
            zr += z[c];
        }
    }
}

// ---------------------------------------------------------------------------
// MFMA attention output (R8-verified structure; S/Z bf16 vector loads).
// ---------------------------------------------------------------------------
__global__ __launch_bounds__(256) void attn_out_mfma(const __hip_bfloat16* __restrict__ qvh,
                                                     const __hip_bfloat16* __restrict__ Sbh,
                                                     const __hip_bfloat16* __restrict__ Zbh,
                                                     const __hip_bfloat16* __restrict__ VTh,
                                                     __hip_bfloat16* __restrict__ attn) {
    __shared__ __bf16 Pbuf[4 * 64 * 68];
    const int tid = threadIdx.x, wave = tid >> 6, lane = tid & 63;
    const int quad = lane >> 4, lr = lane & 15;
    const int bh = blockIdx.y, b = bh >> 4, h = bh & 15;
    const int c = blockIdx.x * 4 + wave;
    const size_t t0 = (size_t)b * L_ + c * CK_;
    const __bf16* qb = (const __bf16*)qvh;
    const __bf16* Sb = (const __bf16*)Sbh;
    const __bf16* Zb = (const __bf16*)Zbh;
    const __bf16* VT = (const __bf16*)VTh;
    __bf16* P = Pbuf + wave * (64 * 68);

    bf16x8 qf[4][2];
#pragma unroll
    for (int ls = 0; ls < 4; ++ls)
#pragma unroll
        for (int kk = 0; kk < 2; ++kk)
            qf[ls][kk] = *(const bf16x8*)&qb[(t0 + ls * 16 + lr) * 3072 + h * 64 + kk * 32 + quad * 8];

    f32x4 num[4][4], den[4];
#pragma unroll
    for (int i = 0; i < 4; ++i) {
        den[i] = (f32x4){0.f, 0.f, 0.f, 0.f};
#pragma unroll
        for (int j = 0; j < 4; ++j) num[i][j] = (f32x4){0.f, 0.f, 0.f, 0.f};
    }

    bf16x8 zf[2];
#pragma unroll
    for (int kk = 0; kk < 2; ++kk)
        zf[kk] = *(const bf16x8*)&Zb[((size_t)(c * 32 + bh) << 6) + kk * 32 + quad * 8];
#pragma unroll
    for (int ls = 0; ls < 4; ++ls)
#pragma unroll
        for (int kk = 0; kk < 2; ++kk)
            den[ls] = __builtin_amdgcn_mfma_f32_16x16x32_bf16(qf[ls][kk], zf[kk], den[ls], 0, 0, 0);

#pragma unroll
    for (int es = 0; es < 4; ++es) {
        bf16x8 sf[2];
#pragma unroll
        for (int kk = 0; kk < 2; ++kk)
            sf[kk] = *(const bf16x8*)&Sb[((size_t)(c * 32 + bh) << 12)
                                         + (es * 16 + lr) * 64 + kk * 32 + quad * 8];
#pragma unroll
        for (int ls = 0; ls < 4; ++ls)
#pragma unroll
            for (int kk = 0; kk < 2; ++kk)
                num[ls][es] = __builtin_amdgcn_mfma_f32_16x16x32_bf16(
                    qf[ls][kk], sf[kk], num[ls][es], 0, 0, 0);
    }

    bf16x8 kf[4][2];
#pragma unroll
    for (int ms = 0; ms < 4; ++ms)
#pragma unroll
        for (int kk = 0; kk < 2; ++kk)
            kf[ms][kk] = *(const bf16x8*)&qb[(t0 + ms * 16 + lr) * 3072 + 1024 + h * 64 + kk * 32 + quad * 8];

#pragma unroll
    for (int ls = 0; ls < 4; ++ls) {
#pragma unroll
        for (int ms = 0; ms < 4; ++ms) {
            int off = (ls * 16 + lr) * 68 + ms * 16 + quad * 4;
            if (ms <= ls) {
                f32x4 pt = (f32x4){0.f, 0.f, 0.f, 0.f};
                pt = __builtin_amdgcn_mfma_f32_16x16x32_bf16(kf[ms][0], qf[ls][0], pt, 0, 0, 0);
                pt = __builtin_amdgcn_mfma_f32_16x16x32_bf16(kf[ms][1], qf[ls][1], pt, 0, 0, 0);
                ushort4 u;
                if (ms == ls) {
                    u.x = (quad * 4 + 0 > lr) ? 0 : f2u(pt[0]);
                    u.y = (quad * 4 + 1 > lr) ? 0 : f2u(pt[1]);
                    u.z = (quad * 4 + 2 > lr) ? 0 : f2u(pt[2]);
                    u.w = (quad * 4 + 3 > lr) ? 0 : f2u(pt[3]);
                } else {
                    u = (ushort4){f2u(pt[0]), f2u(pt[1]), f2u(pt[2]), f2u(pt[3])};
                }
                *(ushort4*)&P[off] = u;
            } else {
                *(ushort4*)&P[off] = (ushort4){0, 0, 0, 0};
            }
        }
    }

    U8 of;
#pragma unroll
    for (int j = 0; j < 8; ++j) of.e[j] = f2b(1.0f);

#pragma unroll
    for (int kk = 0; kk < 2; ++kk) {
        U8 pf[4];
#pragma unroll
        for (int ls = 0; ls < 4; ++ls) {
            pf[ls].half2[0] = *(const bf16x4*)&P[(ls * 16 + lr) * 68 + kk * 32 + quad * 8];
            pf[ls].half2[1] = *(const bf16x4*)&P[(ls * 16 + lr) * 68 + kk * 32 + quad * 8 + 4];
        }
        bf16x8 vf[4];
#pragma unroll
        for (int es = 0; es < 4; ++es)
            vf[es] = *(const bf16x8*)&VT[((size_t)((b * 16 + h) * 64 + es * 16 + lr) << 12)
                                         + c * CK_ + kk * 32 + quad * 8];
#pragma unroll
        for (int ls = 0; ls < 4; ++ls) {
            den[ls] = __builtin_amdgcn_mfma_f32_16x16x32_bf16(pf[ls].v, of.v, den[ls], 0, 0, 0);
#pragma unroll
            for (int es = 0; es < 4; ++es)
                num[ls][es] = __builtin_amdgcn_mfma_f32_16x16x32_bf16(
                    pf[ls].v, vf[es], num[ls][es], 0, 0, 0);
        }
    }

#pragma unroll
    for (int ls = 0; ls < 4; ++ls) {
#pragma unroll
        for (int r = 0; r < 4; ++r) {
            float inv = 1.f / fmaxf(den[ls][r], 1e-6f);
            size_t row = (t0 + ls * 16 + quad * 4 + r) * 1024 + h * 64;
#pragma unroll
            for (int es = 0; es < 4; ++es)
                attn[row + es * 16 + lr] = __float2bfloat16(num[ls][es][r] * inv);
        }
    }
}

// ---------------------------------------------------------------------------
extern "C" void kernel_launch(void* const* d_in, const int* in_sizes, int n_in,
                              void* d_out, int out_size, void* d_ws, size_t ws_size,
                              hipStream_t stream) {
    (void)ws_size; (void)out_size;
    const float *x = nullptr, *Wqkv = nullptr, *Wout = nullptr;
    for (int i = 0; i < n_in; ++i) {
        if (in_sizes[i] == 8388608)      x    = (const float*)d_in[i];
        else if (in_sizes[i] == 3145728) Wqkv = (const float*)d_in[i];
        else if (in_sizes[i] == 1048576) Wout = (const float*)d_in[i];
    }

    __hip_bfloat16* ws16  = (__hip_bfloat16*)d_ws;
    __hip_bfloat16* xb    = ws16;                       //  8388608 (attn aliases)
    __hip_bfloat16* attn  = ws16;
    __hip_bfloat16* Wqkvb = ws16 + 8388608;             //  3145728
    __hip_bfloat16* Woutb = Wqkvb + 3145728;            //  1048576
    __hip_bfloat16* qv    = Woutb + 1048576;            // 25165824
    __hip_bfloat16* VT    = qv + 25165824;              //  8388608
    __hip_bfloat16* KT    = VT + 8388608;               //  8388608
    __hip_bfloat16* Sb    = KT + 8388608;               //  8388608
    __hip_bfloat16* Zb    = Sb + 8388608;               //   131072

    cast_f32_bf16<<<8388608 / 1024, 256, 0, stream>>>(x, xb, 8388608);
    cast_f32_bf16<<<3145728 / 1024, 256, 0, stream>>>(Wqkv, Wqkvb, 3145728);
    cast_f32_bf16<<<1048576 / 1024, 256, 0, stream>>>(Wout, Woutb, 1048576);

    // 1. qv (+KT,+VT) = feature_map(xb @ Wqkvb^T)  — 3-buf counted-vmcnt + T1
    gemm_mfma3<1><<<dim3(3072 / 128, 8192 / 128), 256, 0, stream>>>(
        (const __bf16*)xb, (const __bf16*)Wqkvb, qv, KT, VT, B_ * L_, 3 * E_, E_);
    // 2. per-chunk states via MFMA (bf16 out)
    chunk_state_mfma<<<dim3(16, B_ * H_), 256, 0, stream>>>(KT, VT, Sb, Zb);
    // 3. exclusive prefix over 64 chunks (register-resident scan)
    prefix64<<<dim3(16, B_ * H_), 256, 0, stream>>>(Sb, Zb);
    // 4. MFMA attention output -> attn bf16
    attn_out_mfma<<<dim3(16, B_ * H_), 256, 0, stream>>>(qv, Sb, Zb, VT, attn);
    // 5. out = attn @ Woutb^T, f32 — same 3-buf counted-vmcnt + T1 template
    gemm_mfma3<0><<<dim3(1024 / 128, 8192 / 128), 256, 0, stream>>>(
        (const __bf16*)attn, (const __bf16*)Woutb, d_out, nullptr, nullptr, B_ * L_, E_, E_);
}

// Round 7
// 230.751 us; speedup vs baseline: 1.2530x; 1.0088x over previous
//
#include <hip/hip_runtime.h>
#include <hip/hip_bf16.h>
#include <math.h>

#define B_ 2
#define L_ 4096
#define E_ 1024
#define H_ 16
#define D_ 64
#define CK_ 64
#define NC_ 64

typedef __bf16 bf16x8 __attribute__((ext_vector_type(8)));
typedef __bf16 bf16x4 __attribute__((ext_vector_type(4)));
typedef float  f32x4  __attribute__((ext_vector_type(4)));

__device__ __forceinline__ float fmap1(float x) { return x > 0.f ? x + 1.f : expf(x); }
__device__ __forceinline__ __bf16 f2b(float f) {
    __hip_bfloat16 h = __float2bfloat16(f); return *reinterpret_cast<__bf16*>(&h);
}
__device__ __forceinline__ unsigned short f2u(float f) {
    __hip_bfloat16 h = __float2bfloat16(f); return *reinterpret_cast<unsigned short*>(&h);
}

union U8 { bf16x8 v; __bf16 e[8]; bf16x4 half2[2]; };

__device__ __forceinline__ void async16(const __bf16* g, __bf16* lds) {
    __builtin_amdgcn_global_load_lds(
        (const __attribute__((address_space(1))) void*)g,
        (__attribute__((address_space(3))) void*)lds, 16, 0, 0);
}

// Coalesced readback+store from a wave-private [64][68] bf16 LDS tile:
// lane = rr*8+cc covers 8 rows x 128B per pass -> full 64B lines, no
// write-allocate RMW fetch.
__device__ __forceinline__ void flush_tile(const __bf16* rt, __hip_bfloat16* dst,
                                           size_t row_stride, int lane) {
    const int rr = lane >> 3, cc8 = (lane & 7) << 3;
#pragma unroll
    for (int p = 0; p < 8; ++p) {
        const int row = (p << 3) + rr;
        uint2 lo = *(const uint2*)&rt[row * 68 + cc8];
        uint2 hi = *(const uint2*)&rt[row * 68 + cc8 + 4];
        uint4 o = {lo.x, lo.y, hi.x, hi.y};
        *(uint4*)&dst[(size_t)row * row_stride + cc8] = o;
    }
}

// ---------------------------------------------------------------------------
__global__ __launch_bounds__(256) void cast_f32_bf16(const float* __restrict__ in,
                                                     __hip_bfloat16* __restrict__ out, int n) {
    int i = (blockIdx.x * 256 + threadIdx.x) << 2;
    if (i < n) {
        float4 v = *(const float4*)(in + i);
        ushort4 o = {f2u(v.x), f2u(v.y), f2u(v.z), f2u(v.w)};
        *(ushort4*)(out + i) = o;
    }
}

// ---------------------------------------------------------------------------
// MFMA bf16 GEMM: C = A*Bw^T. 128x128 tile, BK=32, 4 waves 2x2, 4x4 16x16x32.
// r4-verified staging: 3 LDS buffers, distance-2 prefetch, counted vmcnt(4),
// one raw s_barrier/step. r6: bijective XCD-chunked swizzle (T1).
// r7: epilogue retile through wave-private LDS -> all output stores are
// full-line dwordx4 (kills the ~34MB write-allocate RMW fetch seen in PMC).
// ---------------------------------------------------------------------------
#define WVMC(n) do { asm volatile("s_waitcnt vmcnt(" #n ")" ::: "memory"); \
    __builtin_amdgcn_sched_barrier(0); } while (0)

template<int EPI>
__global__ __launch_bounds__(256) void gemm_mfma3(const __bf16* __restrict__ A,
                                                  const __bf16* __restrict__ Bw,
                                                  void* __restrict__ Cv,
                                                  __hip_bfloat16* __restrict__ KT,
                                                  __hip_bfloat16* __restrict__ VT,
                                                  int M, int N, int K) {
    __shared__ alignas(16) __bf16 As[3 * 4096];
    __shared__ alignas(16) __bf16 Bs[3 * 4096];
    const int tid = threadIdx.x;
    const int wave = tid >> 6, lane = tid & 63;
    const int wm = wave >> 1, wn = wave & 1;
    const int lq = lane >> 4, lr = lane & 15;

    // XCD-chunked bijective swizzle (T1): nwg % 8 == 0 at both call sites.
    const int nwg = gridDim.x * gridDim.y;
    const int bid = blockIdx.y * gridDim.x + blockIdx.x;
    const int cpx = nwg >> 3;
    const int wgid = (bid & 7) * cpx + (bid >> 3);
    const int bx = wgid % gridDim.x, by = wgid / gridDim.x;
    const int m0 = by * 128, n0 = bx * 128;

    const int NS = K >> 5;

    f32x4 acc[4][4];
#pragma unroll
    for (int i = 0; i < 4; ++i)
#pragma unroll
        for (int j = 0; j < 4; ++j) acc[i][j] = (f32x4){0.f, 0.f, 0.f, 0.f};

    const int stg_r = lane >> 2, stg_c = (lane & 3) << 3;
    const __bf16* Ag0 = A + (size_t)(m0 + (wave << 4) + stg_r) * K + stg_c;
    const __bf16* Ag1 = A + (size_t)(m0 + 64 + (wave << 4) + stg_r) * K + stg_c;
    const __bf16* Bg0 = Bw + (size_t)(n0 + (wave << 4) + stg_r) * K + stg_c;
    const __bf16* Bg1 = Bw + (size_t)(n0 + 64 + (wave << 4) + stg_r) * K + stg_c;
    const int dl0 = (wave << 9), dl1 = ((wave + 4) << 9);

#define STG3(bi, t) do { const int ko_ = (t) << 5; \
    async16(Ag0 + ko_, &As[(bi) * 4096 + dl0]); \
    async16(Ag1 + ko_, &As[(bi) * 4096 + dl1]); \
    async16(Bg0 + ko_, &Bs[(bi) * 4096 + dl0]); \
    async16(Bg1 + ko_, &Bs[(bi) * 4096 + dl1]); } while (0)

    STG3(0, 0);
    STG3(1, 1);
    WVMC(4);
    __builtin_amdgcn_s_barrier();

    int bi = 0, bn = 2;
    for (int t = 0; t < NS; ++t) {
        if (t + 2 < NS) STG3(bn, t + 2);
        bf16x8 af[4], bfr[4];
#pragma unroll
        for (int tt = 0; tt < 4; ++tt) {
            af[tt]  = *(const bf16x8*)&As[bi * 4096 + ((wm << 6) + (tt << 4) + lr) * 32 + (lq << 3)];
            bfr[tt] = *(const bf16x8*)&Bs[bi * 4096 + ((wn << 6) + (tt << 4) + lr) * 32 + (lq << 3)];
        }
#pragma unroll
        for (int mt = 0; mt < 4; ++mt)
#pragma unroll
            for (int nt = 0; nt < 4; ++nt)
                acc[mt][nt] = __builtin_amdgcn_mfma_f32_16x16x32_bf16(
                    af[mt], bfr[nt], acc[mt][nt], 0, 0, 0);
        if (t < NS - 2)       { WVMC(4); }
        else if (t == NS - 2) { WVMC(0); }
        __builtin_amdgcn_s_barrier();
        bi = (bi == 2) ? 0 : bi + 1;
        bn = (bn == 2) ? 0 : bn + 1;
    }

    // ---- epilogue (r7: LDS retile, full-line stores) ----
    const int M0 = m0 + (wm << 6);
    const int N0 = n0 + (wn << 6);
    if (EPI == 1) {
        // All waves are past the final barrier: As/Bs free. Wave-private tile.
        __bf16* rt = ((wave & 2) ? Bs : As) + (wave & 1) * 4352;   // 64x68
        const int w = n0 >> 10;   // uniform: 128-tile never straddles 1024
        __hip_bfloat16* Cb = (__hip_bfloat16*)Cv;

        if (w <= 1) {   // natural-layout pass: q~ (w0) / k~ (w1)
#pragma unroll
            for (int mt = 0; mt < 4; ++mt)
#pragma unroll
                for (int nt = 0; nt < 4; ++nt)
#pragma unroll
                    for (int r = 0; r < 4; ++r) {
                        float v = fmap1(acc[mt][nt][r]);
                        if (w == 0) v *= 0.125f;
                        rt[((mt << 4) + (lq << 2) + r) * 68 + (nt << 4) + lr] = f2b(v);
                    }
            flush_tile(rt, Cb + (size_t)M0 * N + N0, N, lane);
        }
        if (w >= 1) {   // transposed pass: w1 -> KT, w2 -> VT
#pragma unroll
            for (int mt = 0; mt < 4; ++mt)
#pragma unroll
                for (int nt = 0; nt < 4; ++nt) {
                    ushort4 u;
                    if (w == 1)
                        u = (ushort4){f2u(fmap1(acc[mt][nt][0])), f2u(fmap1(acc[mt][nt][1])),
                                      f2u(fmap1(acc[mt][nt][2])), f2u(fmap1(acc[mt][nt][3]))};
                    else
                        u = (ushort4){f2u(acc[mt][nt][0]), f2u(acc[mt][nt][1]),
                                      f2u(acc[mt][nt][2]), f2u(acc[mt][nt][3])};
                    // transposed: row = n_local, cols m_local..m_local+3
                    *(ushort4*)&rt[((nt << 4) + lr) * 68 + (mt << 4) + (lq << 2)] = u;
                }
            const int hh = (N0 >> 6) & 15;
            const int bb2 = M0 >> 12;
            const int l0 = M0 & 4095;
            __hip_bfloat16* T = (w == 1) ? KT : VT;
            flush_tile(rt, T + (((size_t)((bb2 * 16 + hh) << 6)) << 12) + l0, 4096, lane);
        }
    } else {
        // f32 out: 16 lanes x 4B = 64B/line per instr already -> keep direct.
#pragma unroll
        for (int mt = 0; mt < 4; ++mt)
#pragma unroll
            for (int nt = 0; nt < 4; ++nt) {
                int m = M0 + (mt << 4) + (lq << 2);
                int n = N0 + (nt << 4) + lr;
#pragma unroll
                for (int r = 0; r < 4; ++r)
                    ((float*)Cv)[(size_t)(m + r) * N + n] = acc[mt][nt][r];
            }
    }
#undef STG3
}

// ---------------------------------------------------------------------------
// MFMA per-chunk state: S_T[e][d] = sum_l VT[e][l]*KT[d][l]; Z[d] = sum_l KT[d][l].
// grid (16, 32). r7: S-store retiled through wave-private LDS (full-line).
// ---------------------------------------------------------------------------
__global__ __launch_bounds__(256) void chunk_state_mfma(const __hip_bfloat16* __restrict__ KTh,
                                                        const __hip_bfloat16* __restrict__ VTh,
                                                        __hip_bfloat16* __restrict__ Sb,
                                                        __hip_bfloat16* __restrict__ Zb) {
    __shared__ alignas(16) __bf16 rts[4][64 * 68];
    const int tid = threadIdx.x, wave = tid >> 6, lane = tid & 63;
    const int quad = lane >> 4, lr = lane & 15;
    const int bh = blockIdx.y;
    const int c = blockIdx.x * 4 + wave;
    const __bf16* KT = (const __bf16*)KTh;
    const __bf16* VT = (const __bf16*)VTh;
    __bf16* rt = rts[wave];

    bf16x8 vt[4][2], kt[4][2];
#pragma unroll
    for (int t = 0; t < 4; ++t)
#pragma unroll
        for (int kk = 0; kk < 2; ++kk) {
            size_t rowoff = ((size_t)(bh * 64 + t * 16 + lr) << 12) + c * CK_ + kk * 32 + quad * 8;
            vt[t][kk] = *(const bf16x8*)&VT[rowoff];
            kt[t][kk] = *(const bf16x8*)&KT[rowoff];
        }

    U8 of;
#pragma unroll
    for (int j = 0; j < 8; ++j) of.e[j] = f2b(1.0f);

#pragma unroll
    for (int es = 0; es < 4; ++es) {
#pragma unroll
        for (int dt = 0; dt < 4; ++dt) {
            f32x4 acc = (f32x4){0.f, 0.f, 0.f, 0.f};
            acc = __builtin_amdgcn_mfma_f32_16x16x32_bf16(vt[es][0], kt[dt][0], acc, 0, 0, 0);
            acc = __builtin_amdgcn_mfma_f32_16x16x32_bf16(vt[es][1], kt[dt][1], acc, 0, 0, 0);
#pragma unroll
            for (int r = 0; r < 4; ++r)
                rt[((es << 4) + (quad << 2) + r) * 68 + (dt << 4) + lr] = f2b(acc[r]);
        }
    }
    flush_tile(rt, Sb + ((size_t)(c * 32 + bh) << 12), 64, lane);

#pragma unroll
    for (int dt = 0; dt < 4; ++dt) {
        f32x4 z = (f32x4){0.f, 0.f, 0.f, 0.f};
        z = __builtin_amdgcn_mfma_f32_16x16x32_bf16(kt[dt][0], of.v, z, 0, 0, 0);
        z = __builtin_amdgcn_mfma_f32_16x16x32_bf16(kt[dt][1], of.v, z, 0, 0, 0);
        if (lr == 0) {
#pragma unroll
            for (int r = 0; r < 4; ++r)
                Zb[((c * 32 + bh) << 6) + dt * 16 + quad * 4 + r] = __float2bfloat16(z[r]);
        }
    }
}

// ---------------------------------------------------------------------------
// Exclusive prefix over 64 chunks, register-resident. grid (16, 32).
// ---------------------------------------------------------------------------
__global__ __launch_bounds__(256) void prefix64(__hip_bfloat16* __restrict__ Sb,
                                                __hip_bfloat16* __restrict__ Zb) {
    const int bh = blockIdx.y;
    const int idx = blockIdx.x * 256 + threadIdx.x;   // 0..4095
    float v[NC_];
#pragma unroll
    for (int c = 0; c < NC_; ++c)
        v[c] = __bfloat162float(Sb[((size_t)(c * 32 + bh) << 12) + idx]);
    float run = 0.f;
#pragma unroll
    for (int c = 0; c < NC_; ++c) {
        Sb[((size_t)(c * 32 + bh) << 12) + idx] = __float2bfloat16(run);
        run += v[c];
    }
    if (blockIdx.x == 0 && threadIdx.x < 64) {
        float z[NC_];
#pragma unroll
        for (int c = 0; c < NC_; ++c)
            z[c] = __bfloat162float(Zb[((c * 32 + bh) << 6) + threadIdx.x]);
        float zr = 0.f;
#pragma unroll
        for (int c = 0; c < NC_; ++c) {
            Zb[((c * 32 + bh) << 6) + threadIdx.x] = __float2bfloat16(zr);
            zr += z[c];
        }
    }
}

// ---------------------------------------------------------------------------
// MFMA attention output. r7: final store retiled through Pbuf (full-line).
// ---------------------------------------------------------------------------
__global__ __launch_bounds__(256) void attn_out_mfma(const __hip_bfloat16* __restrict__ qvh,
                                                     const __hip_bfloat16* __restrict__ Sbh,
                                                     const __hip_bfloat16* __restrict__ Zbh,
                                                     const __hip_bfloat16* __restrict__ VTh,
                                                     __hip_bfloat16* __restrict__ attn) {
    __shared__ __bf16 Pbuf[4 * 64 * 68];
    const int tid = threadIdx.x, wave = tid >> 6, lane = tid & 63;
    const int quad = lane >> 4, lr = lane & 15;
    const int bh = blockIdx.y, b = bh >> 4, h = bh & 15;
    const int c = blockIdx.x * 4 + wave;
    const size_t t0 = (size_t)b * L_ + c * CK_;
    const __bf16* qb = (const __bf16*)qvh;
    const __bf16* Sb = (const __bf16*)Sbh;
    const __bf16* Zb = (const __bf16*)Zbh;
    const __bf16* VT = (const __bf16*)VTh;
    __bf16* P = Pbuf + wave * (64 * 68);

    bf16x8 qf[4][2];
#pragma unroll
    for (int ls = 0; ls < 4; ++ls)
#pragma unroll
        for (int kk = 0; kk < 2; ++kk)
            qf[ls][kk] = *(const bf16x8*)&qb[(t0 + ls * 16 + lr) * 3072 + h * 64 + kk * 32 + quad * 8];

    f32x4 num[4][4], den[4];
#pragma unroll
    for (int i = 0; i < 4; ++i) {
        den[i] = (f32x4){0.f, 0.f, 0.f, 0.f};
#pragma unroll
        for (int j = 0; j < 4; ++j) num[i][j] = (f32x4){0.f, 0.f, 0.f, 0.f};
    }

    bf16x8 zf[2];
#pragma unroll
    for (int kk = 0; kk < 2; ++kk)
        zf[kk] = *(const bf16x8*)&Zb[((size_t)(c * 32 + bh) << 6) + kk * 32 + quad * 8];
#pragma unroll
    for (int ls = 0; ls < 4; ++ls)
#pragma unroll
        for (int kk = 0; kk < 2; ++kk)
            den[ls] = __builtin_amdgcn_mfma_f32_16x16x32_bf16(qf[ls][kk], zf[kk], den[ls], 0, 0, 0);

#pragma unroll
    for (int es = 0; es < 4; ++es) {
        bf16x8 sf[2];
#pragma unroll
        for (int kk = 0; kk < 2; ++kk)
            sf[kk] = *(const bf16x8*)&Sb[((size_t)(c * 32 + bh) << 12)
                                         + (es * 16 + lr) * 64 + kk * 32 + quad * 8];
#pragma unroll
        for (int ls = 0; ls < 4; ++ls)
#pragma unroll
            for (int kk = 0; kk < 2; ++kk)
                num[ls][es] = __builtin_amdgcn_mfma_f32_16x16x32_bf16(
                    qf[ls][kk], sf[kk], num[ls][es], 0, 0, 0);
    }

    bf16x8 kf[4][2];
#pragma unroll
    for (int ms = 0; ms < 4; ++ms)
#pragma unroll
        for (int kk = 0; kk < 2; ++kk)
            kf[ms][kk] = *(const bf16x8*)&qb[(t0 + ms * 16 + lr) * 3072 + 1024 + h * 64 + kk * 32 + quad * 8];

#pragma unroll
    for (int ls = 0; ls < 4; ++ls) {
#pragma unroll
        for (int ms = 0; ms < 4; ++ms) {
            int off = (ls * 16 + lr) * 68 + ms * 16 + quad * 4;
            if (ms <= ls) {
                f32x4 pt = (f32x4){0.f, 0.f, 0.f, 0.f};
                pt = __builtin_amdgcn_mfma_f32_16x16x32_bf16(kf[ms][0], qf[ls][0], pt, 0, 0, 0);
                pt = __builtin_amdgcn_mfma_f32_16x16x32_bf16(kf[ms][1], qf[ls][1], pt, 0, 0, 0);
                ushort4 u;
                if (ms == ls) {
                    u.x = (quad * 4 + 0 > lr) ? 0 : f2u(pt[0]);
                    u.y = (quad * 4 + 1 > lr) ? 0 : f2u(pt[1]);
                    u.z = (quad * 4 + 2 > lr) ? 0 : f2u(pt[2]);
                    u.w = (quad * 4 + 3 > lr) ? 0 : f2u(pt[3]);
                } else {
                    u = (ushort4){f2u(pt[0]), f2u(pt[1]), f2u(pt[2]), f2u(pt[3])};
                }
                *(ushort4*)&P[off] = u;
            } else {
                *(ushort4*)&P[off] = (ushort4){0, 0, 0, 0};
            }
        }
    }

    U8 of;
#pragma unroll
    for (int j = 0; j < 8; ++j) of.e[j] = f2b(1.0f);

#pragma unroll
    for (int kk = 0; kk < 2; ++kk) {
        U8 pf[4];
#pragma unroll
        for (int ls = 0; ls < 4; ++ls) {
            pf[ls].half2[0] = *(const bf16x4*)&P[(ls * 16 + lr) * 68 + kk * 32 + quad * 8];
            pf[ls].half2[1] = *(const bf16x4*)&P[(ls * 16 + lr) * 68 + kk * 32 + quad * 8 + 4];
        }
        bf16x8 vf[4];
#pragma unroll
        for (int es = 0; es < 4; ++es)
            vf[es] = *(const bf16x8*)&VT[((size_t)((b * 16 + h) * 64 + es * 16 + lr) << 12)
                                         + c * CK_ + kk * 32 + quad * 8];
#pragma unroll
        for (int ls = 0; ls < 4; ++ls) {
            den[ls] = __builtin_amdgcn_mfma_f32_16x16x32_bf16(pf[ls].v, of.v, den[ls], 0, 0, 0);
#pragma unroll
            for (int es = 0; es < 4; ++es)
                num[ls][es] = __builtin_amdgcn_mfma_f32_16x16x32_bf16(
                    pf[ls].v, vf[es], num[ls][es], 0, 0, 0);
        }
    }

    // r7: retile result into P (done with pf reads; wave-private) and store
    // full-line dwordx4: 8 lanes x 16B = 128B contiguous per attn row.
#pragma unroll
    for (int ls = 0; ls < 4; ++ls)
#pragma unroll
        for (int r = 0; r < 4; ++r) {
            float inv = 1.f / fmaxf(den[ls][r], 1e-6f);
#pragma unroll
            for (int es = 0; es < 4; ++es)
                P[((ls << 4) + (quad << 2) + r) * 68 + (es << 4) + lr] =
                    f2b(num[ls][es][r] * inv);
        }
    flush_tile(P, attn + t0 * 1024 + (h << 6), 1024, lane);
}

// ---------------------------------------------------------------------------
extern "C" void kernel_launch(void* const* d_in, const int* in_sizes, int n_in,
                              void* d_out, int out_size, void* d_ws, size_t ws_size,
                              hipStream_t stream) {
    (void)ws_size; (void)out_size;
    const float *x = nullptr, *Wqkv = nullptr, *Wout = nullptr;
    for (int i = 0; i < n_in; ++i) {
        if (in_sizes[i] == 8388608)      x    = (const float*)d_in[i];
        else if (in_sizes[i] == 3145728) Wqkv = (const float*)d_in[i];
        else if (in_sizes[i] == 1048576) Wout = (const float*)d_in[i];
    }

    __hip_bfloat16* ws16  = (__hip_bfloat16*)d_ws;
    __hip_bfloat16* xb    = ws16;                       //  8388608 (attn aliases)
    __hip_bfloat16* attn  = ws16;
    __hip_bfloat16* Wqkvb = ws16 + 8388608;             //  3145728
    __hip_bfloat16* Woutb = Wqkvb + 3145728;            //  1048576
    __hip_bfloat16* qv    = Woutb + 1048576;            // 25165824
    __hip_bfloat16* VT    = qv + 25165824;              //  8388608
    __hip_bfloat16* KT    = VT + 8388608;               //  8388608
    __hip_bfloat16* Sb    = KT + 8388608;               //  8388608
    __hip_bfloat16* Zb    = Sb + 8388608;               //   131072

    cast_f32_bf16<<<8388608 / 1024, 256, 0, stream>>>(x, xb, 8388608);
    cast_f32_bf16<<<3145728 / 1024, 256, 0, stream>>>(Wqkv, Wqkvb, 3145728);
    cast_f32_bf16<<<1048576 / 1024, 256, 0, stream>>>(Wout, Woutb, 1048576);

    // 1. qv (+KT,+VT) = feature_map(xb @ Wqkvb^T)  — 3-buf counted-vmcnt + T1 + retile
    gemm_mfma3<1><<<dim3(3072 / 128, 8192 / 128), 256, 0, stream>>>(
        (const __bf16*)xb, (const __bf16*)Wqkvb, qv, KT, VT, B_ * L_, 3 * E_, E_);
    // 2. per-chunk states via MFMA (bf16 out, retiled stores)
    chunk_state_mfma<<<dim3(16, B_ * H_), 256, 0, stream>>>(KT, VT, Sb, Zb);
    // 3. exclusive prefix over 64 chunks (register-resident scan)
    prefix64<<<dim3(16, B_ * H_), 256, 0, stream>>>(Sb, Zb);
    // 4. MFMA attention output -> attn bf16 (retiled stores)
    attn_out_mfma<<<dim3(16, B_ * H_), 256, 0, stream>>>(qv, Sb, Zb, VT, attn);
    // 5. out = attn @ Woutb^T, f32 — 3-buf counted-vmcnt + T1 (already coalesced)
    gemm_mfma3<0><<<dim3(1024 / 128, 8192 / 128), 256, 0, stream>>>(
        (const __bf16*)attn, (const __bf16*)Woutb, d_out, nullptr, nullptr, B_ * L_, E_, E_);
}